// Round 4
// baseline (261.437 us; speedup 1.0000x reference)
//
#include <hip/hip_runtime.h>
#include <cstdint>
#include <cstddef>

typedef _Float16 f16;
typedef __attribute__((ext_vector_type(4))) _Float16 f16x4;
typedef __attribute__((ext_vector_type(8))) _Float16 f16x8;
typedef __attribute__((ext_vector_type(4))) float f32x4;

static constexpr int BB = 4;
static constexpr int SS = 2048;
static constexpr int EE = 1024;

static constexpr int BM = 128, BN = 128;   // legacy core tile (scores/pv)

// async global->LDS, 16B per lane. LDS dest must be wave-uniform base + lane*16.
__device__ __forceinline__ void gload_lds16(const f16* g, f16* l) {
  __builtin_amdgcn_global_load_lds(
      (const __attribute__((address_space(1))) void*)g,
      (__attribute__((address_space(3))) void*)l, 16, 0, 0);
}

struct Frag {
  int lane, wave, wy, wx, l16, quad, quadx;
  __device__ Frag() {
    const int tid = threadIdx.x;
    lane = tid & 63; wave = tid >> 6;
    wy = wave >> 1; wx = wave & 1;
    l16 = lane & 15; quad = lane >> 4;
    quadx = quad ^ ((l16 >> 2) & 3);   // XOR-swizzled chunk select
  }
};

// Staging swizzle: LDS chunk c holds global chunk (row=c>>2, kc=(c&3)^((c>>4)&3)).
// 128x32 f16 tile = 512 chunks of 16B; 2 chunks/thread.
struct Stager {
  const f16* g[2];
  int l[2];
  __device__ void init(const f16* base, int ld, const Frag& fr) {
#pragma unroll
    for (int i = 0; i < 2; ++i) {
      const int c = fr.wave * 128 + i * 64 + fr.lane;
      const int row = c >> 2;
      const int kcs = (c & 3) ^ ((c >> 4) & 3);
      g[i] = base + (size_t)row * ld + kcs * 8;
      l[i] = c * 8;
    }
  }
  __device__ __forceinline__ void stage(int ko, f16* lds) const {
    gload_lds16(g[0] + ko, lds + l[0]);
    gload_lds16(g[1] + ko, lds + l[1]);
  }
};

// One 16-MFMA round from a staged 128x32 buffer pair
__device__ __forceinline__ void mfma_round(
    const f16* __restrict__ Ash, const f16* __restrict__ Bsh,
    f32x4 acc[4][4], const Frag& fr)
{
  f16x8 af[4], bf[4];
#pragma unroll
  for (int mi = 0; mi < 4; ++mi)
    af[mi] = *(const f16x8*)(Ash + (fr.wy * 64 + mi * 16 + fr.l16) * 32 + fr.quadx * 8);
#pragma unroll
  for (int ni = 0; ni < 4; ++ni)
    bf[ni] = *(const f16x8*)(Bsh + (fr.wx * 64 + ni * 16 + fr.l16) * 32 + fr.quadx * 8);
#pragma unroll
  for (int mi = 0; mi < 4; ++mi)
#pragma unroll
    for (int ni = 0; ni < 4; ++ni)
      acc[mi][ni] = __builtin_amdgcn_mfma_f32_16x16x32_f16(af[mi], bf[ni], acc[mi][ni], 0, 0, 0);
}

// C[m,n] = sum_k A[m,k]*Bt[n,k]; 2x(128x32) staged per barrier -> 32 MFMA/barrier
__device__ __forceinline__ void gemm_core(
    const f16* __restrict__ A, const f16* __restrict__ Bt,
    int lda, int ldb, int kOuter,
    f16* __restrict__ Ash, f16* __restrict__ Bsh,   // each [2][128*32]
    f32x4 acc[4][4], const Frag& fr)
{
  Stager sa, sb;
  sa.init(A, lda, fr);
  sb.init(Bt, ldb, fr);
  for (int kt = 0; kt < kOuter; ++kt) {
    const int ko = kt * 64;
    sa.stage(ko, Ash);       sa.stage(ko + 32, Ash + 128 * 32);
    sb.stage(ko, Bsh);       sb.stage(ko + 32, Bsh + 128 * 32);
    __syncthreads();
    mfma_round(Ash, Bsh, acc, fr);
    mfma_round(Ash + 128 * 32, Bsh + 128 * 32, acc, fr);
    __syncthreads();
  }
}

// ---------------- single cast launch: X (2M f4) then Wq/Wk/Wv (256K f4 each) ----------------
__global__ __launch_bounds__(256) void cast_all_kernel(
    const float* __restrict__ xs,
    const float* __restrict__ w0, const float* __restrict__ w1, const float* __restrict__ w2,
    f16* __restrict__ Xh, f16* __restrict__ o0, f16* __restrict__ o1, f16* __restrict__ o2)
{
  const int i = blockIdx.x * 256 + threadIdx.x;   // f4 index < 2883584 (exact grid)
  const float* src; f16* dst; int idx;
  if (i < 2097152) {
    src = xs; dst = Xh; idx = i;
  } else {
    const int j = i - 2097152;
    const int w = j >> 18;          // 262144 f4 per weight matrix
    idx = j & 262143;
    src = (w == 0) ? w0 : (w == 1) ? w1 : w2;
    dst = (w == 0) ? o0 : (w == 1) ? o1 : o2;
  }
  const float4 f = ((const float4*)src)[idx];
  f16x4 h;
  h.x = (f16)f.x; h.y = (f16)f.y; h.z = (f16)f.z; h.w = (f16)f.w;
  ((f16x4*)dst)[idx] = h;
}

// ==================== proj4: 256x256 tiles (m201 geometry), 2-buf, 2 barriers/K-tile ====================
// Grid 384 blocks, 512 threads (8 waves as 2M x 4N -> wave-tile 128x64), LDS 128KB.
//   t in [0,128):   Q  = X[8192x1024] . Wq^T   (mt 0..31, nt 0..3)
//   t in [128,256): K  = X . Wk^T
//   t in [256,384): Vt = Wv[1024x1024] . X^T   (mt 0..3, nt 0..31)
// Per K-tile kt (BK=64, NT=16):
//   s_barrier                  // all waves done reading buf nxt (tile kt-1)
//   stage tile kt+1 -> nxt     // 8 gload_lds/thread (A 4, B 4)
//   s_waitcnt vmcnt(8)         // drain tile kt's 8 (one compute-phase in flight), keep kt+1's
//   s_barrier                  // joint: ALL waves' tile-kt loads landed
//   2 x { 12 ds_read_b128 ; 32 MFMA }   (ks halves; compiler-scheduled lgkm)
// Wave-tile 128x64: LDS reads (128+64)*64*2B = 24KB/wave vs 64 MFMA -> MFMA-dominant
// (per CU: MFMA 2483 cyc vs LDS-port ~1900 cyc), unlike the old 64x64 (1242 vs 1936).
// XOR chunk swizzle c' = c ^ (row&7); swizzle depends only on l16&7 so fragment
// offsets are one base + mi*1024 (ds_read immediates) -> low VGPR.
__global__ __launch_bounds__(512, 1) void proj4_kernel(
    const f16* __restrict__ X,
    const f16* __restrict__ Wq, const f16* __restrict__ Wk, const f16* __restrict__ Wv,
    const float* __restrict__ bq, const float* __restrict__ bk, const float* __restrict__ bv,
    f16* __restrict__ Qh, f16* __restrict__ Kh, f16* __restrict__ Vt)
{
  __shared__ __align__(16) f16 smem[65536];   // A: 2x16384 f16, B: 2x16384 f16 = 128KB
  const int tid = threadIdx.x;
  const int lane = tid & 63, wave = tid >> 6;
  const int wy = wave >> 2, wx = wave & 3;    // 2x4 waves -> per-wave 128x64 output
  const int l16 = lane & 15, quad = lane >> 4;

  const int t = blockIdx.x;
  const int which = (t < 128) ? 0 : (t < 256) ? 1 : 2;
  const int u = t - which * 128;
  const int c8 = u & 7, g = u >> 3;           // c8 = XCD residue, g in 0..15
  const f16* Abase; const f16* Bbase;
  int mt, nt;
  if (which < 2) {
    mt = c8 + 8 * (g & 3);                    // blocks sharing X-tile -> same XCD
    nt = g >> 2;                              // 0..3
    Abase = X + (size_t)mt * 256 * EE;
    Bbase = ((which == 0) ? Wq : Wk) + (size_t)nt * 256 * EE;
  } else {
    nt = c8 + 8 * (g & 3);                    // blocks sharing X-tile -> same XCD
    mt = g >> 2;                              // 0..3
    Abase = Wv + (size_t)mt * 256 * EE;
    Bbase = X + (size_t)nt * 256 * EE;
  }

  // ---- staging: A/B tiles each 256x64 f16 = 2048 chunks of 16B; 4 chunks/thread each
  const f16* gA[4]; const f16* gB[4]; int lc[4];
#pragma unroll
  for (int j = 0; j < 4; ++j) {
    const int slot = j * 512 + tid;
    const int r = slot >> 3, cg = (slot & 7) ^ (r & 7);   // inverse-swizzled source
    gA[j] = Abase + (size_t)r * EE + cg * 8;
    gB[j] = Bbase + (size_t)r * EE + cg * 8;
    lc[j] = slot * 8;
  }

  auto stageTile = [&](int bi, int kt) {
    const int ko = kt * 64;
    f16* ab = smem + bi * 16384;
    f16* bb = smem + 32768 + bi * 16384;
#pragma unroll
    for (int j = 0; j < 4; ++j) gload_lds16(gA[j] + ko, ab + lc[j]);
#pragma unroll
    for (int j = 0; j < 4; ++j) gload_lds16(gB[j] + ko, bb + lc[j]);
  };

  // ---- fragment read bases (f16 units); swizzle uses only l16&7 so +mi*1024 walks rows
  int obA[2], obB[2];
#pragma unroll
  for (int ks = 0; ks < 2; ++ks) {
    const int rA = wy * 128 + l16;
    const int rB = wx * 64 + l16;
    obA[ks] = (rA * 8 + ((ks * 4 + quad) ^ (rA & 7))) * 8;
    obB[ks] = (rB * 8 + ((ks * 4 + quad) ^ (rB & 7))) * 8;
  }

  // ---- prologue
  stageTile(0, 0);

  f32x4 acc[8][4] = {};

  constexpr int NT = 16;   // 1024 / 64
  for (int kt = 0; kt < NT; ++kt) {
    const int cur = kt & 1, nxt = cur ^ 1;
    __builtin_amdgcn_s_barrier();                    // buf nxt (tile kt-1) fully consumed
    if (kt + 1 < NT) {
      stageTile(nxt, kt + 1);
      asm volatile("s_waitcnt vmcnt(8)" ::: "memory");   // tile kt landed, kt+1 in flight
    } else {
      asm volatile("s_waitcnt vmcnt(0)" ::: "memory");
    }
    __builtin_amdgcn_s_barrier();                    // all waves' tile-kt loads landed

    const f16* Ac = smem + cur * 16384;
    const f16* Bc = smem + 32768 + cur * 16384;
#pragma unroll
    for (int ks = 0; ks < 2; ++ks) {
      f16x8 a[8], b[4];
#pragma unroll
      for (int mi = 0; mi < 8; ++mi) a[mi] = *(const f16x8*)(Ac + obA[ks] + mi * 1024);
#pragma unroll
      for (int ni = 0; ni < 4; ++ni) b[ni] = *(const f16x8*)(Bc + obB[ks] + ni * 1024);
      __builtin_amdgcn_s_setprio(1);
#pragma unroll
      for (int mi = 0; mi < 8; ++mi)
#pragma unroll
        for (int ni = 0; ni < 4; ++ni)
          acc[mi][ni] = __builtin_amdgcn_mfma_f32_16x16x32_f16(a[mi], b[ni], acc[mi][ni], 0, 0, 0);
      __builtin_amdgcn_s_setprio(0);
    }
  }

  // ---- epilogue
  const int r0 = mt * 256 + wy * 128;
  const int c0 = nt * 256 + wx * 64;
  if (which < 2) {
    const float* bias = (which == 0) ? bq : bk;
    f16* out = (which == 0) ? Qh : Kh;
#pragma unroll
    for (int ni = 0; ni < 4; ++ni) {
      const int c = c0 + ni * 16 + l16;
      const float bz = bias[c];
#pragma unroll
      for (int mi = 0; mi < 8; ++mi) {
        const int r = r0 + mi * 16 + quad * 4;
#pragma unroll
        for (int i = 0; i < 4; ++i)
          out[(size_t)(r + i) * EE + c] = (f16)(acc[mi][ni][i] + bz);
      }
    }
  } else {
#pragma unroll
    for (int ni = 0; ni < 4; ++ni) {
      const int cg = c0 + ni * 16 + l16;        // global s in [0, 8192)
      const int b = cg >> 11, sc = cg & 2047;
      f16* out = Vt + (size_t)b * EE * SS;
#pragma unroll
      for (int mi = 0; mi < 8; ++mi) {
        const int r = r0 + mi * 16 + quad * 4;  // e row
#pragma unroll
        for (int i = 0; i < 4; ++i)
          out[(size_t)(r + i) * SS + sc] = (f16)(acc[mi][ni][i] + bv[r + i]);
      }
    }
  }
}

// ---------------- scores: Sc[q,k] = (Q[q,:] . K[k,:]) / 32, lower-tri tiles only ----------------
__global__ __launch_bounds__(256) void scores_kernel(
    const f16* __restrict__ Q, const f16* __restrict__ Kh, f16* __restrict__ Sc)
{
  __shared__ __align__(16) f16 Ash[2][BM * 32];
  __shared__ __align__(16) f16 Bsh[2][BN * 32];
  const int t = blockIdx.x, b = blockIdx.z;
  int qt = 0;
  while ((qt + 1) * (qt + 2) / 2 <= t) ++qt;
  const int kt = t - qt * (qt + 1) / 2;
  const f16* A  = Q  + (size_t)b * SS * EE + (size_t)qt * BM * EE;
  const f16* Bp = Kh + (size_t)b * SS * EE + (size_t)kt * BN * EE;
  f16* out = Sc + (size_t)b * SS * SS;
  Frag fr;
  f32x4 acc[4][4] = {};
  gemm_core(A, Bp, EE, EE, EE / 64, Ash[0], Bsh[0], acc, fr);
  const float scale = 0.03125f;   // 1/sqrt(1024)
#pragma unroll
  for (int ni = 0; ni < 4; ++ni) {
    const int c = kt * BN + fr.wx * 64 + ni * 16 + fr.l16;
#pragma unroll
    for (int mi = 0; mi < 4; ++mi) {
      const int r = qt * BM + fr.wy * 64 + mi * 16 + fr.quad * 4;
#pragma unroll
      for (int i = 0; i < 4; ++i)
        out[(size_t)(r + i) * SS + c] = (f16)(acc[mi][ni][i] * scale);
    }
  }
}

// ---------------- in-place causal softmax over row q (vectorized f16x8) ----------------
__global__ __launch_bounds__(256) void softmax_kernel(f16* __restrict__ Sc)
{
  const int q = blockIdx.x, b = blockIdx.y;
  f16* row = Sc + (size_t)b * SS * SS + (size_t)q * SS;
  const int n = q + 1;
  const int kend = ((q >> 7) + 1) << 7;   // PV reads K up to this 128-boundary
  const int tid = threadIdx.x;
  const int i0 = tid * 8;

  float v[8];
  if (i0 + 8 <= n) {
    const f16x8 h = *(const f16x8*)(row + i0);
#pragma unroll
    for (int j = 0; j < 8; ++j) v[j] = (float)h[j];
  } else {
#pragma unroll
    for (int j = 0; j < 8; ++j) {
      const int idx = i0 + j;
      v[j] = (idx < n) ? (float)row[idx] : -1e30f;
    }
  }

  float m = v[0];
#pragma unroll
  for (int j = 1; j < 8; ++j) m = fmaxf(m, v[j]);
  __shared__ float red[4];
#pragma unroll
  for (int off = 32; off > 0; off >>= 1) m = fmaxf(m, __shfl_down(m, off));
  if ((tid & 63) == 0) red[tid >> 6] = m;
  __syncthreads();
  m = fmaxf(fmaxf(red[0], red[1]), fmaxf(red[2], red[3]));

  float sum = 0.f;
#pragma unroll
  for (int j = 0; j < 8; ++j) {
    v[j] = (i0 + j < n) ? __expf(v[j] - m) : 0.f;
    sum += v[j];
  }
#pragma unroll
  for (int off = 32; off > 0; off >>= 1) sum += __shfl_down(sum, off);
  __syncthreads();
  if ((tid & 63) == 0) red[tid >> 6] = sum;
  __syncthreads();
  sum = red[0] + red[1] + red[2] + red[3];
  const float inv = 1.f / sum;

  if (i0 < kend) {
    f16x8 h;
#pragma unroll
    for (int j = 0; j < 8; ++j) h[j] = (f16)(v[j] * inv);   // v==0 beyond n
    *(f16x8*)(row + i0) = h;
  }
}

// ---------------- PV: Y[q,e] = sum_{k<=q} P[q,k] * Vt[e,k], fp32 out ----------------
// Flat 512-block grid with complementary-pair remap: block t and t+256 map to
// qt=15-qh and qt=qh (same et,b) -> uniform per-CU K-tile load.
__global__ __launch_bounds__(256) void pv_kernel(
    const f16* __restrict__ P, const f16* __restrict__ Vt, float* __restrict__ Y)
{
  __shared__ __align__(16) f16 Ash[2][BM * 32];
  __shared__ __align__(16) f16 Bsh[2][BN * 32];
  const int t = blockIdx.x;
  const int u = t & 255;
  const int qh = u & 7, et = (u >> 3) & 7, b = u >> 6;
  const int qt = (t < 256) ? (15 - qh) : qh;
  const f16* A  = P  + (size_t)b * SS * SS + (size_t)qt * BM * SS;
  const f16* Bp = Vt + (size_t)b * EE * SS + (size_t)et * BN * SS;
  float* out = Y + (size_t)b * SS * EE;
  Frag fr;
  f32x4 acc[4][4] = {};
  gemm_core(A, Bp, SS, SS, (qt + 1) * 2, Ash[0], Bsh[0], acc, fr);
#pragma unroll
  for (int ni = 0; ni < 4; ++ni) {
    const int c = et * BN + fr.wx * 64 + ni * 16 + fr.l16;
#pragma unroll
    for (int mi = 0; mi < 4; ++mi) {
      const int r = qt * BM + fr.wy * 64 + mi * 16 + fr.quad * 4;
#pragma unroll
      for (int i = 0; i < 4; ++i)
        out[(size_t)(r + i) * EE + c] = acc[mi][ni][i];
    }
  }
}

extern "C" void kernel_launch(void* const* d_in, const int* in_sizes, int n_in,
                              void* d_out, int out_size, void* d_ws, size_t ws_size,
                              hipStream_t stream)
{
  const float* xs  = (const float*)d_in[0];
  const float* WQw = (const float*)d_in[1];
  const float* WQb = (const float*)d_in[2];
  const float* WKw = (const float*)d_in[3];
  const float* WKb = (const float*)d_in[4];
  const float* WVw = (const float*)d_in[5];
  const float* WVb = (const float*)d_in[6];

  const size_t ME = (size_t)BB * SS * EE;   // 8M tokens*dim
  const size_t WE = (size_t)EE * EE;        // 1M weight elems

  f16* Xh = (f16*)d_ws;
  f16* Wq = Xh + ME;
  f16* Wk = Wq + WE;
  f16* Wv = Wk + WE;
  f16* Qh = Wv + WE;
  f16* Kh = Qh + ME;
  f16* Vt = Kh + ME;
  f16* Sc = Vt + ME;   // BB*SS*SS f16 = 32 MiB

  // 1) casts (one launch): (8M + 3*1M)/4 = 2883584 f4 -> 11264 blocks exact
  cast_all_kernel<<<dim3(11264), 256, 0, stream>>>(
      xs, WQw, WKw, WVw, Xh, Wq, Wk, Wv);

  // 2) projections: 256x256 tiles, 384 blocks, 512 threads
  proj4_kernel<<<dim3(384), 512, 0, stream>>>(
      Xh, Wq, Wk, Wv, WQb, WKb, WVb, Qh, Kh, Vt);

  // 3) scores (lower-tri tiles)
  const int nTri = (SS / BM) * (SS / BM + 1) / 2;   // 136
  scores_kernel<<<dim3(nTri, 1, BB), 256, 0, stream>>>(Qh, Kh, Sc);

  // 4) softmax
  softmax_kernel<<<dim3(SS, BB), 256, 0, stream>>>(Sc);

  // 5) PV
  pv_kernel<<<dim3(512), 256, 0, stream>>>(Sc, Vt, (float*)d_out);
}

// Round 5
// 258.728 us; speedup vs baseline: 1.0105x; 1.0105x over previous
//
#include <hip/hip_runtime.h>
#include <cstdint>
#include <cstddef>

typedef _Float16 f16;
typedef __attribute__((ext_vector_type(4))) _Float16 f16x4;
typedef __attribute__((ext_vector_type(8))) _Float16 f16x8;
typedef __attribute__((ext_vector_type(4))) float f32x4;

static constexpr int BB = 4;
static constexpr int SS = 2048;
static constexpr int EE = 1024;

static constexpr int BM = 128, BN = 128;   // legacy core tile (scores/pv)

// async global->LDS, 16B per lane. LDS dest must be wave-uniform base + lane*16.
__device__ __forceinline__ void gload_lds16(const f16* g, f16* l) {
  __builtin_amdgcn_global_load_lds(
      (const __attribute__((address_space(1))) void*)g,
      (__attribute__((address_space(3))) void*)l, 16, 0, 0);
}

struct Frag {
  int lane, wave, wy, wx, l16, quad, quadx;
  __device__ Frag() {
    const int tid = threadIdx.x;
    lane = tid & 63; wave = tid >> 6;
    wy = wave >> 1; wx = wave & 1;
    l16 = lane & 15; quad = lane >> 4;
    quadx = quad ^ ((l16 >> 2) & 3);   // XOR-swizzled chunk select
  }
};

// Staging swizzle: LDS chunk c holds global chunk (row=c>>2, kc=(c&3)^((c>>4)&3)).
// 128x32 f16 tile = 512 chunks of 16B; 2 chunks/thread.
struct Stager {
  const f16* g[2];
  int l[2];
  __device__ void init(const f16* base, int ld, const Frag& fr) {
#pragma unroll
    for (int i = 0; i < 2; ++i) {
      const int c = fr.wave * 128 + i * 64 + fr.lane;
      const int row = c >> 2;
      const int kcs = (c & 3) ^ ((c >> 4) & 3);
      g[i] = base + (size_t)row * ld + kcs * 8;
      l[i] = c * 8;
    }
  }
  __device__ __forceinline__ void stage(int ko, f16* lds) const {
    gload_lds16(g[0] + ko, lds + l[0]);
    gload_lds16(g[1] + ko, lds + l[1]);
  }
};

// One 16-MFMA round from a staged 128x32 buffer pair
__device__ __forceinline__ void mfma_round(
    const f16* __restrict__ Ash, const f16* __restrict__ Bsh,
    f32x4 acc[4][4], const Frag& fr)
{
  f16x8 af[4], bf[4];
#pragma unroll
  for (int mi = 0; mi < 4; ++mi)
    af[mi] = *(const f16x8*)(Ash + (fr.wy * 64 + mi * 16 + fr.l16) * 32 + fr.quadx * 8);
#pragma unroll
  for (int ni = 0; ni < 4; ++ni)
    bf[ni] = *(const f16x8*)(Bsh + (fr.wx * 64 + ni * 16 + fr.l16) * 32 + fr.quadx * 8);
#pragma unroll
  for (int mi = 0; mi < 4; ++mi)
#pragma unroll
    for (int ni = 0; ni < 4; ++ni)
      acc[mi][ni] = __builtin_amdgcn_mfma_f32_16x16x32_f16(af[mi], bf[ni], acc[mi][ni], 0, 0, 0);
}

// C[m,n] = sum_k A[m,k]*Bt[n,k]; 2x(128x32) staged per barrier -> 32 MFMA/barrier
__device__ __forceinline__ void gemm_core(
    const f16* __restrict__ A, const f16* __restrict__ Bt,
    int lda, int ldb, int kOuter,
    f16* __restrict__ Ash, f16* __restrict__ Bsh,   // each [2][128*32]
    f32x4 acc[4][4], const Frag& fr)
{
  Stager sa, sb;
  sa.init(A, lda, fr);
  sb.init(Bt, ldb, fr);
  for (int kt = 0; kt < kOuter; ++kt) {
    const int ko = kt * 64;
    sa.stage(ko, Ash);       sa.stage(ko + 32, Ash + 128 * 32);
    sb.stage(ko, Bsh);       sb.stage(ko + 32, Bsh + 128 * 32);
    __syncthreads();
    mfma_round(Ash, Bsh, acc, fr);
    mfma_round(Ash + 128 * 32, Bsh + 128 * 32, acc, fr);
    __syncthreads();
  }
}

// ---------------- single cast launch: X (2M f4) then Wq/Wk/Wv (256K f4 each) ----------------
__global__ __launch_bounds__(256) void cast_all_kernel(
    const float* __restrict__ xs,
    const float* __restrict__ w0, const float* __restrict__ w1, const float* __restrict__ w2,
    f16* __restrict__ Xh, f16* __restrict__ o0, f16* __restrict__ o1, f16* __restrict__ o2)
{
  const int i = blockIdx.x * 256 + threadIdx.x;   // f4 index < 2883584 (exact grid)
  const float* src; f16* dst; int idx;
  if (i < 2097152) {
    src = xs; dst = Xh; idx = i;
  } else {
    const int j = i - 2097152;
    const int w = j >> 18;          // 262144 f4 per weight matrix
    idx = j & 262143;
    src = (w == 0) ? w0 : (w == 1) ? w1 : w2;
    dst = (w == 0) ? o0 : (w == 1) ? o1 : o2;
  }
  const float4 f = ((const float4*)src)[idx];
  f16x4 h;
  h.x = (f16)f.x; h.y = (f16)f.y; h.z = (f16)f.z; h.w = (f16)f.w;
  ((f16x4*)dst)[idx] = h;
}

// ==================== proj5: 256x256 tile, faithful 8-phase schedule (T3+T4+T5, m201) ==========
// Grid 384, 512 threads (8 waves 2Mx4N -> wave-tile 128x64), LDS 128KB:
//   2 dbuf x { A: 2 halves of 128x64 f16, B: 2 halves }, half = 8192 f16 (16KB).
//   dbuf is tile-parity: even K-tiles -> dbuf0, odd -> dbuf1.
// Per K-tile: 4 quadrant-phases, each {ds_read subtile ; stage ONE half ; barrier ;
// lgkmcnt(0) ; setprio(1) 16 MFMA setprio(0) ; barrier}:
//   q1 (mh0,nh0): read a0(8)+b0(4); stage A0(Tx)   q2 (mh0,nh1): read b1(4); stage A1(Tx)
//   q3 (mh1,nh1): read a1(8);       stage B0(Ty)   q4 (mh1,nh0): no reads;   stage B1(Ty)
// where for iter i (tiles 2i,2i+1): half-iter0: Tx=2i+1, Ty=2i+2; half-iter1: Tx=2i+2, Ty=2i+3.
// Liveness: a wave ds_reads its A-half at q1,q3 and B-half at q1,q2 -> B-halves of the
// compute-dbuf free after q2's end-barrier, A-halves after q3's -> each stage slot targets
// a freed region (stage issue point is after the previous phase's end-barrier).
// vmcnt(4) ONLY at q4 of each half-iter (T4, never 0 mid-loop): outstanding there = 6
// halves (12 loads); the 4 halves of the next compute tile are the oldest 8 -> vmcnt(4)
// forces them landed; the barrier after it publishes across waves. Last iter: vmcnt(0).
// Reads are chunk-XOR-swizzled (c^(row&7)); source pre-inverse-swizzled, LDS dest linear.
__global__ __launch_bounds__(512, 1) void proj5_kernel(
    const f16* __restrict__ X,
    const f16* __restrict__ Wq, const f16* __restrict__ Wk, const f16* __restrict__ Wv,
    const float* __restrict__ bq, const float* __restrict__ bk, const float* __restrict__ bv,
    f16* __restrict__ Qh, f16* __restrict__ Kh, f16* __restrict__ Vt)
{
  __shared__ __align__(16) f16 smem[65536];   // A: 4x8192 (dbuf,half), B: +32768 same
  const int tid = threadIdx.x;
  const int lane = tid & 63, wave = tid >> 6;
  const int wy = wave >> 2, wx = wave & 3;    // 2x4 waves -> per-wave 128x64 output
  const int l16 = lane & 15, quad = lane >> 4;

  const int t = blockIdx.x;
  const int which = (t < 128) ? 0 : (t < 256) ? 1 : 2;
  const int u = t - which * 128;
  const int c8 = u & 7, g = u >> 3;           // c8 = XCD residue, g in 0..15
  const f16* Abase; const f16* Bbase;
  int mt, nt;
  if (which < 2) {
    mt = c8 + 8 * (g & 3);                    // blocks sharing X-tile -> same XCD
    nt = g >> 2;                              // 0..3
    Abase = X + (size_t)mt * 256 * EE;
    Bbase = ((which == 0) ? Wq : Wk) + (size_t)nt * 256 * EE;
  } else {
    nt = c8 + 8 * (g & 3);                    // blocks sharing X-tile -> same XCD
    mt = g >> 2;                              // 0..3
    Abase = Wv + (size_t)mt * 256 * EE;
    Bbase = X + (size_t)nt * 256 * EE;
  }

  // ---- staging descriptors: half = 128 rows x 64 f16 = 1024 chunks; 2 chunks/thread
  const f16* gA[2][2]; const f16* gB[2][2]; int lso[2];
#pragma unroll
  for (int j = 0; j < 2; ++j) {
    const int s = j * 512 + tid;
    const int r = s >> 3, cg = (s & 7) ^ (r & 7);   // inverse-swizzled source
    lso[j] = s * 8;
#pragma unroll
    for (int h = 0; h < 2; ++h) {
      gA[h][j] = Abase + (size_t)(h * 128 + r) * EE + cg * 8;
      gB[h][j] = Bbase + (size_t)(h * 128 + r) * EE + cg * 8;
    }
  }

  auto stA = [&](int h, int x) {                     // stage A-half h of tile x
    if (x < 16) {
      const int ko = x * 64;
      f16* dst = smem + ((x & 1) * 2 + h) * 8192;
      gload_lds16(gA[h][0] + ko, dst + lso[0]);
      gload_lds16(gA[h][1] + ko, dst + lso[1]);
    }
  };
  auto stB = [&](int h, int x) {
    if (x < 16) {
      const int ko = x * 64;
      f16* dst = smem + 32768 + ((x & 1) * 2 + h) * 8192;
      gload_lds16(gB[h][0] + ko, dst + lso[0]);
      gload_lds16(gB[h][1] + ko, dst + lso[1]);
    }
  };

  // ---- fragment read offsets within a half (f16 units); row&7 == l16&7 for all frags
  int obA[2], obB[2];
#pragma unroll
  for (int ks = 0; ks < 2; ++ks) {
    const int rB = (wx & 1) * 64 + l16;
    obA[ks] = (l16 * 8 + ((ks * 4 + quad) ^ (l16 & 7))) * 8;   // + mi*1024
    obB[ks] = (rB * 8 + ((ks * 4 + quad) ^ (rB & 7))) * 8;     // + ni*1024
  }

#define PBAR() asm volatile("s_barrier" ::: "memory")
#define LGKM0() do { asm volatile("s_waitcnt lgkmcnt(0)" ::: "memory"); \
                     __builtin_amdgcn_sched_barrier(0); } while (0)
#define QUAD(MH, NH, AF, BF) do { \
  __builtin_amdgcn_s_setprio(1); \
  _Pragma("unroll") for (int m = 0; m < 4; ++m) \
  _Pragma("unroll") for (int n = 0; n < 2; ++n) \
  _Pragma("unroll") for (int ks = 0; ks < 2; ++ks) \
    acc[(MH)*4+m][(NH)*2+n] = __builtin_amdgcn_mfma_f32_16x16x32_f16( \
        AF[m][ks], BF[n][ks], acc[(MH)*4+m][(NH)*2+n], 0, 0, 0); \
  __builtin_amdgcn_s_setprio(0); } while (0)

  // ---- prologue: tile0 (all 4 halves, oldest) then tile1's B halves -> 12 loads
  stB(0, 0); stB(1, 0); stA(0, 0); stA(1, 0);
  stB(0, 1); stB(1, 1);
  asm volatile("s_waitcnt vmcnt(4)" ::: "memory");   // tile0's 8 oldest landed
  __builtin_amdgcn_s_barrier();

  f32x4 acc[8][4] = {};

  for (int i = 0; i < 8; ++i) {
    const bool last = (i == 7);
#pragma unroll
    for (int h2 = 0; h2 < 2; ++h2) {
      const int Tx = h2 ? 2 * i + 2 : 2 * i + 1;   // A halves staged q1/q2
      const int Ty = h2 ? 2 * i + 3 : 2 * i + 2;   // B halves staged q3/q4
      const f16* Ard = smem + (h2 * 2 + wy) * 8192;
      const f16* Brd = smem + 32768 + (h2 * 2 + (wx >> 1)) * 8192;
      f16x8 a0[4][2], a1[4][2], b0[2][2], b1[2][2];

      // ---- q1 (mh0, nh0): read a0, b0 ; stage A0(Tx)
#pragma unroll
      for (int m = 0; m < 4; ++m)
#pragma unroll
        for (int ks = 0; ks < 2; ++ks) a0[m][ks] = *(const f16x8*)(Ard + obA[ks] + m * 1024);
#pragma unroll
      for (int n = 0; n < 2; ++n)
#pragma unroll
        for (int ks = 0; ks < 2; ++ks) b0[n][ks] = *(const f16x8*)(Brd + obB[ks] + n * 1024);
      stA(0, Tx);
      PBAR(); LGKM0();
      QUAD(0, 0, a0, b0);
      PBAR();

      // ---- q2 (mh0, nh1): read b1 ; stage A1(Tx)
#pragma unroll
      for (int n = 0; n < 2; ++n)
#pragma unroll
        for (int ks = 0; ks < 2; ++ks) b1[n][ks] = *(const f16x8*)(Brd + obB[ks] + (n + 2) * 1024);
      stA(1, Tx);
      PBAR(); LGKM0();
      QUAD(0, 1, a0, b1);
      PBAR();

      // ---- q3 (mh1, nh1): read a1 ; stage B0(Ty)  (compute-dbuf B-halves freed after q2)
#pragma unroll
      for (int m = 0; m < 4; ++m)
#pragma unroll
        for (int ks = 0; ks < 2; ++ks) a1[m][ks] = *(const f16x8*)(Ard + obA[ks] + (m + 4) * 1024);
      stB(0, Ty);
      PBAR(); LGKM0();
      QUAD(1, 1, a1, b1);
      PBAR();

      // ---- q4 (mh1, nh0): no reads (b0 in regs) ; stage B1(Ty) ; counted vmcnt
      stB(1, Ty);
      if (last && h2 == 0)      asm volatile("s_waitcnt vmcnt(0)" ::: "memory");
      else if (!(last && h2 == 1)) asm volatile("s_waitcnt vmcnt(4)" ::: "memory");
      PBAR();
      QUAD(1, 0, a1, b0);
      PBAR();
    }
  }
#undef PBAR
#undef LGKM0
#undef QUAD

  // ---- epilogue
  const int r0 = mt * 256 + wy * 128;
  const int c0 = nt * 256 + wx * 64;
  if (which < 2) {
    const float* bias = (which == 0) ? bq : bk;
    f16* out = (which == 0) ? Qh : Kh;
#pragma unroll
    for (int ni = 0; ni < 4; ++ni) {
      const int c = c0 + ni * 16 + l16;
      const float bz = bias[c];
#pragma unroll
      for (int mi = 0; mi < 8; ++mi) {
        const int r = r0 + mi * 16 + quad * 4;
#pragma unroll
        for (int i = 0; i < 4; ++i)
          out[(size_t)(r + i) * EE + c] = (f16)(acc[mi][ni][i] + bz);
      }
    }
  } else {
#pragma unroll
    for (int ni = 0; ni < 4; ++ni) {
      const int cg = c0 + ni * 16 + l16;        // global s in [0, 8192)
      const int b = cg >> 11, sc = cg & 2047;
      f16* out = Vt + (size_t)b * EE * SS;
#pragma unroll
      for (int mi = 0; mi < 8; ++mi) {
        const int r = r0 + mi * 16 + quad * 4;  // e row
#pragma unroll
        for (int i = 0; i < 4; ++i)
          out[(size_t)(r + i) * SS + sc] = (f16)(acc[mi][ni][i] + bv[r + i]);
      }
    }
  }
}

// ---------------- scores: Sc[q,k] = (Q[q,:] . K[k,:]) / 32, lower-tri tiles only ----------------
__global__ __launch_bounds__(256) void scores_kernel(
    const f16* __restrict__ Q, const f16* __restrict__ Kh, f16* __restrict__ Sc)
{
  __shared__ __align__(16) f16 Ash[2][BM * 32];
  __shared__ __align__(16) f16 Bsh[2][BN * 32];
  const int t = blockIdx.x, b = blockIdx.z;
  int qt = 0;
  while ((qt + 1) * (qt + 2) / 2 <= t) ++qt;
  const int kt = t - qt * (qt + 1) / 2;
  const f16* A  = Q  + (size_t)b * SS * EE + (size_t)qt * BM * EE;
  const f16* Bp = Kh + (size_t)b * SS * EE + (size_t)kt * BN * EE;
  f16* out = Sc + (size_t)b * SS * SS;
  Frag fr;
  f32x4 acc[4][4] = {};
  gemm_core(A, Bp, EE, EE, EE / 64, Ash[0], Bsh[0], acc, fr);
  const float scale = 0.03125f;   // 1/sqrt(1024)
#pragma unroll
  for (int ni = 0; ni < 4; ++ni) {
    const int c = kt * BN + fr.wx * 64 + ni * 16 + fr.l16;
#pragma unroll
    for (int mi = 0; mi < 4; ++mi) {
      const int r = qt * BM + fr.wy * 64 + mi * 16 + fr.quad * 4;
#pragma unroll
      for (int i = 0; i < 4; ++i)
        out[(size_t)(r + i) * SS + c] = (f16)(acc[mi][ni][i] * scale);
    }
  }
}

// ---------------- in-place causal softmax over row q (vectorized f16x8) ----------------
__global__ __launch_bounds__(256) void softmax_kernel(f16* __restrict__ Sc)
{
  const int q = blockIdx.x, b = blockIdx.y;
  f16* row = Sc + (size_t)b * SS * SS + (size_t)q * SS;
  const int n = q + 1;
  const int kend = ((q >> 7) + 1) << 7;   // PV reads K up to this 128-boundary
  const int tid = threadIdx.x;
  const int i0 = tid * 8;

  float v[8];
  if (i0 + 8 <= n) {
    const f16x8 h = *(const f16x8*)(row + i0);
#pragma unroll
    for (int j = 0; j < 8; ++j) v[j] = (float)h[j];
  } else {
#pragma unroll
    for (int j = 0; j < 8; ++j) {
      const int idx = i0 + j;
      v[j] = (idx < n) ? (float)row[idx] : -1e30f;
    }
  }

  float m = v[0];
#pragma unroll
  for (int j = 1; j < 8; ++j) m = fmaxf(m, v[j]);
  __shared__ float red[4];
#pragma unroll
  for (int off = 32; off > 0; off >>= 1) m = fmaxf(m, __shfl_down(m, off));
  if ((tid & 63) == 0) red[tid >> 6] = m;
  __syncthreads();
  m = fmaxf(fmaxf(red[0], red[1]), fmaxf(red[2], red[3]));

  float sum = 0.f;
#pragma unroll
  for (int j = 0; j < 8; ++j) {
    v[j] = (i0 + j < n) ? __expf(v[j] - m) : 0.f;
    sum += v[j];
  }
#pragma unroll
  for (int off = 32; off > 0; off >>= 1) sum += __shfl_down(sum, off);
  __syncthreads();
  if ((tid & 63) == 0) red[tid >> 6] = sum;
  __syncthreads();
  sum = red[0] + red[1] + red[2] + red[3];
  const float inv = 1.f / sum;

  if (i0 < kend) {
    f16x8 h;
#pragma unroll
    for (int j = 0; j < 8; ++j) h[j] = (f16)(v[j] * inv);   // v==0 beyond n
    *(f16x8*)(row + i0) = h;
  }
}

// ---------------- PV: Y[q,e] = sum_{k<=q} P[q,k] * Vt[e,k], fp32 out ----------------
// Flat 512-block grid with complementary-pair remap: block t and t+256 map to
// qt=15-qh and qt=qh (same et,b) -> uniform per-CU K-tile load.
__global__ __launch_bounds__(256) void pv_kernel(
    const f16* __restrict__ P, const f16* __restrict__ Vt, float* __restrict__ Y)
{
  __shared__ __align__(16) f16 Ash[2][BM * 32];
  __shared__ __align__(16) f16 Bsh[2][BN * 32];
  const int t = blockIdx.x;
  const int u = t & 255;
  const int qh = u & 7, et = (u >> 3) & 7, b = u >> 6;
  const int qt = (t < 256) ? (15 - qh) : qh;
  const f16* A  = P  + (size_t)b * SS * SS + (size_t)qt * BM * SS;
  const f16* Bp = Vt + (size_t)b * EE * SS + (size_t)et * BN * SS;
  float* out = Y + (size_t)b * SS * EE;
  Frag fr;
  f32x4 acc[4][4] = {};
  gemm_core(A, Bp, SS, SS, (qt + 1) * 2, Ash[0], Bsh[0], acc, fr);
#pragma unroll
  for (int ni = 0; ni < 4; ++ni) {
    const int c = et * BN + fr.wx * 64 + ni * 16 + fr.l16;
#pragma unroll
    for (int mi = 0; mi < 4; ++mi) {
      const int r = qt * BM + fr.wy * 64 + mi * 16 + fr.quad * 4;
#pragma unroll
      for (int i = 0; i < 4; ++i)
        out[(size_t)(r + i) * EE + c] = acc[mi][ni][i];
    }
  }
}

extern "C" void kernel_launch(void* const* d_in, const int* in_sizes, int n_in,
                              void* d_out, int out_size, void* d_ws, size_t ws_size,
                              hipStream_t stream)
{
  const float* xs  = (const float*)d_in[0];
  const float* WQw = (const float*)d_in[1];
  const float* WQb = (const float*)d_in[2];
  const float* WKw = (const float*)d_in[3];
  const float* WKb = (const float*)d_in[4];
  const float* WVw = (const float*)d_in[5];
  const float* WVb = (const float*)d_in[6];

  const size_t ME = (size_t)BB * SS * EE;   // 8M tokens*dim
  const size_t WE = (size_t)EE * EE;        // 1M weight elems

  f16* Xh = (f16*)d_ws;
  f16* Wq = Xh + ME;
  f16* Wk = Wq + WE;
  f16* Wv = Wk + WE;
  f16* Qh = Wv + WE;
  f16* Kh = Qh + ME;
  f16* Vt = Kh + ME;
  f16* Sc = Vt + ME;   // BB*SS*SS f16 = 32 MiB

  // 1) casts (one launch): (8M + 3*1M)/4 = 2883584 f4 -> 11264 blocks exact
  cast_all_kernel<<<dim3(11264), 256, 0, stream>>>(
      xs, WQw, WKw, WVw, Xh, Wq, Wk, Wv);

  // 2) projections: 256x256 tiles, 8-phase schedule, 384 blocks, 512 threads
  proj5_kernel<<<dim3(384), 512, 0, stream>>>(
      Xh, Wq, Wk, Wv, WQb, WKb, WVb, Qh, Kh, Vt);

  // 3) scores (lower-tri tiles)
  const int nTri = (SS / BM) * (SS / BM + 1) / 2;   // 136
  scores_kernel<<<dim3(nTri, 1, BB), 256, 0, stream>>>(Qh, Kh, Sc);

  // 4) softmax
  softmax_kernel<<<dim3(SS, BB), 256, 0, stream>>>(Sc);

  // 5) PV
  pv_kernel<<<dim3(512), 256, 0, stream>>>(Sc, Vt, (float*)d_out);
}